// Round 7
// baseline (200.532 us; speedup 1.0000x reference)
//
#include <hip/hip_runtime.h>
#include <math.h>

#define BB 64
#define SS 512
#define HH 768
#define LL 21
#define STR 513              // eT row stride (513%32==1 -> conflict-free columns)
#define INFF __builtin_huge_valf()

__device__ inline float rlf(float v, int i) {
    return __int_as_float(__builtin_amdgcn_readlane(__float_as_int(v), i));
}
__device__ inline float mx3(float a, float b, float c) { return fmaxf(fmaxf(a, b), c); }
__device__ inline float wmax64(float v) {
    #pragma unroll
    for (int off = 32; off; off >>= 1) v = fmaxf(v, __shfl_xor(v, off));
    return v;
}
__device__ inline float rlmax21(float a) {
    float r0 = mx3(rlf(a, 0), rlf(a, 1), rlf(a, 2));
    float r1 = mx3(rlf(a, 3), rlf(a, 4), rlf(a, 5));
    float r2 = mx3(rlf(a, 6), rlf(a, 7), rlf(a, 8));
    float r3 = mx3(rlf(a, 9), rlf(a, 10), rlf(a, 11));
    float r4 = mx3(rlf(a, 12), rlf(a, 13), rlf(a, 14));
    float r5 = mx3(rlf(a, 15), rlf(a, 16), rlf(a, 17));
    float r6 = mx3(rlf(a, 18), rlf(a, 19), rlf(a, 20));
    return mx3(mx3(r0, r1, r2), mx3(r3, r4, r5), r6);
}

// ---------------- K1: emissions = hidden @ W + b (unchanged from R6) ------
__global__ __launch_bounds__(256) void k_emis(const float* __restrict__ hidden,
                                              const float* __restrict__ W,
                                              const float* __restrict__ bias,
                                              float* __restrict__ em) {
    __shared__ float hA[128][33];
    __shared__ float hB[128][33];
    __shared__ float Wc[2][32][24];
    __shared__ float cmb[128][22];

    int tid = threadIdx.x;
    int kh = tid >> 7;
    int rloc = tid & 127;
    int r0 = blockIdx.x * 128;

    float acc[LL];
    #pragma unroll
    for (int l = 0; l < LL; ++l) acc[l] = 0.f;

    float (*hrow)[33] = kh ? hB : hA;

    for (int c = 0; c < 12; ++c) {
        __syncthreads();
        #pragma unroll
        for (int rep = 0; rep < 4; ++rep) {
            int f = rep * 256 + tid;
            int rr = f >> 3, c4 = f & 7;
            const float* src = hidden + (size_t)(r0 + rr) * HH + c * 32 + c4 * 4;
            float4 va = *reinterpret_cast<const float4*>(src);
            float4 vb = *reinterpret_cast<const float4*>(src + 384);
            int b0 = c4 * 4;
            hA[rr][b0] = va.x; hA[rr][b0 + 1] = va.y; hA[rr][b0 + 2] = va.z; hA[rr][b0 + 3] = va.w;
            hB[rr][b0] = vb.x; hB[rr][b0 + 1] = vb.y; hB[rr][b0 + 2] = vb.z; hB[rr][b0 + 3] = vb.w;
        }
        for (int u = tid; u < 1344; u += 256) {
            int khu = (u >= 672) ? 1 : 0;
            int rem = u - khu * 672;
            int kk = rem / 21, ll = rem - kk * 21;
            Wc[khu][kk][ll] = W[(size_t)(khu * 384 + c * 32 + kk) * LL + ll];
        }
        __syncthreads();
        #pragma unroll 4
        for (int k = 0; k < 32; ++k) {
            float hv = hrow[rloc][k];
            const float* wp = &Wc[kh][k][0];
            float4 w0 = *reinterpret_cast<const float4*>(wp);
            float4 w1 = *reinterpret_cast<const float4*>(wp + 4);
            float4 w2 = *reinterpret_cast<const float4*>(wp + 8);
            float4 w3 = *reinterpret_cast<const float4*>(wp + 12);
            float4 w4 = *reinterpret_cast<const float4*>(wp + 16);
            float w20 = wp[20];
            acc[0]  = fmaf(hv, w0.x, acc[0]);  acc[1]  = fmaf(hv, w0.y, acc[1]);
            acc[2]  = fmaf(hv, w0.z, acc[2]);  acc[3]  = fmaf(hv, w0.w, acc[3]);
            acc[4]  = fmaf(hv, w1.x, acc[4]);  acc[5]  = fmaf(hv, w1.y, acc[5]);
            acc[6]  = fmaf(hv, w1.z, acc[6]);  acc[7]  = fmaf(hv, w1.w, acc[7]);
            acc[8]  = fmaf(hv, w2.x, acc[8]);  acc[9]  = fmaf(hv, w2.y, acc[9]);
            acc[10] = fmaf(hv, w2.z, acc[10]); acc[11] = fmaf(hv, w2.w, acc[11]);
            acc[12] = fmaf(hv, w3.x, acc[12]); acc[13] = fmaf(hv, w3.y, acc[13]);
            acc[14] = fmaf(hv, w3.z, acc[14]); acc[15] = fmaf(hv, w3.w, acc[15]);
            acc[16] = fmaf(hv, w4.x, acc[16]); acc[17] = fmaf(hv, w4.y, acc[17]);
            acc[18] = fmaf(hv, w4.z, acc[18]); acc[19] = fmaf(hv, w4.w, acc[19]);
            acc[20] = fmaf(hv, w20, acc[20]);
        }
    }
    __syncthreads();
    if (kh == 1) {
        #pragma unroll
        for (int l = 0; l < LL; ++l) cmb[rloc][l] = acc[l];
    }
    __syncthreads();
    if (kh == 0) {
        float* emr = em + (size_t)(r0 + rloc) * LL;
        #pragma unroll
        for (int l = 0; l < LL; ++l) emr[l] = acc[l] + cmb[rloc][l] + bias[l];
    }
}

// ---------------- K2: fused scan dispatch ----------------
// blocks 0-63: Viterbi fwd (S[t] -> Sout transposed [b][j][t])
// blocks 64-127: LSE fwd. blocks 128-191: numerator.
// Emissions transposed into LDS (stride 513, conflict-free); 4-step groups
// with A/B register double-buffer; masks/ballots hoisted off serial path.
__global__ __launch_bounds__(64) void k_scan(const float* __restrict__ em,
                                             const int* __restrict__ attn,
                                             const int* __restrict__ labels,
                                             const float* __restrict__ startT,
                                             const float* __restrict__ endT,
                                             const float* __restrict__ trans,
                                             float* __restrict__ num,
                                             float* __restrict__ denom,
                                             float* __restrict__ Sout) {
    __shared__ float eLT[LL * STR];      // 43092 B
    int lane = threadIdx.x;
    int bid = blockIdx.x;
    bool act = lane < LL;
    int jj = act ? lane : (LL - 1);

    if (bid < 128) {
        int b = bid & 63;
        const float* emb = em + (size_t)b * SS * LL;
        const int* mrow = attn + b * SS;

        // stage emissions transposed: eLT[j*513 + t] = em[b][t][j]
        for (int f = lane; f < (SS * LL) / 4; f += 64) {
            float4 v = *reinterpret_cast<const float4*>(emb + 4 * f);
            unsigned e0 = 4u * (unsigned)f;
            { unsigned t = e0 / 21u,       j = e0 - 21u * t;       eLT[j * STR + t] = v.x; }
            { unsigned e = e0 + 1, t = e / 21u, j = e - 21u * t;   eLT[j * STR + t] = v.y; }
            { unsigned e = e0 + 2, t = e / 21u, j = e - 21u * t;   eLT[j * STR + t] = v.z; }
            { unsigned e = e0 + 3, t = e / 21u, j = e - 21u * t;   eLT[j * STR + t] = v.w; }
        }
        __syncthreads();

        int jbase = jj * STR;
        float A0, A1, A2, A3, B0, B1, B2, B3;

#define LDG(P, G) do { int tb4_ = (G) * 4; \
    P##0 = eLT[jbase + tb4_];     P##1 = eLT[jbase + tb4_ + 1]; \
    P##2 = eLT[jbase + tb4_ + 2]; P##3 = eLT[jbase + tb4_ + 3]; } while (0)

        if (bid < 64) {
            // ---------------- Viterbi ----------------
            float Tc[LL];
            #pragma unroll
            for (int i = 0; i < LL; ++i) Tc[i] = trans[i * LL + jj];
            float* Sgj = Sout + (size_t)b * (LL * SS) + jj * SS;

            LDG(A, 0);
            int mkc = mrow[lane], mkn = 0;
            float a = act ? (startT[lane] + A0) : -INFF;

#define VCORE(EMIT, BIT) do { \
    float cc[LL]; \
    _Pragma("unroll") for (int i_ = 0; i_ < LL; ++i_) cc[i_] = rlf(a, i_) + Tc[i_]; \
    float x0 = mx3(cc[0], cc[1], cc[2]),   x1 = mx3(cc[3], cc[4], cc[5]); \
    float x2 = mx3(cc[6], cc[7], cc[8]),   x3 = mx3(cc[9], cc[10], cc[11]); \
    float x4 = mx3(cc[12], cc[13], cc[14]), x5 = mx3(cc[15], cc[16], cc[17]); \
    float x6 = mx3(cc[18], cc[19], cc[20]); \
    float best = mx3(mx3(x0, x1, x2), mx3(x3, x4, x5), x6); \
    bool mt_ = ((mm >> (BIT)) & 1ull) != 0ull; \
    float an_ = best + (EMIT); \
    a = (mt_ && act) ? an_ : a; \
} while (0)

#define VGROUP(P, G, BITB) do { int tb4_ = (G) * 4; \
    float o0_, o1_, o2_, o3_; \
    if (tb4_ == 0) { o0_ = a; } else { VCORE(P##0, (BITB) + 0); o0_ = a; } \
    VCORE(P##1, (BITB) + 1); o1_ = a; \
    VCORE(P##2, (BITB) + 2); o2_ = a; \
    VCORE(P##3, (BITB) + 3); o3_ = a; \
    if (act) *reinterpret_cast<float4*>(Sgj + tb4_) = make_float4(o0_, o1_, o2_, o3_); \
} while (0)

            for (int q = 0; q < 8; ++q) {
                unsigned long long mm = __ballot(mkc != 0);
                if (q < 7) mkn = mrow[(q + 1) * 64 + lane];
                for (int gp = 0; gp < 8; ++gp) {
                    int g = q * 16 + gp * 2;
                    LDG(B, g + 1);
                    VGROUP(A, g, gp * 8);
                    if (g + 2 < 128) LDG(A, g + 2);
                    VGROUP(B, g + 1, gp * 8 + 4);
                }
                mkc = mkn;
            }
#undef VCORE
#undef VGROUP
        } else {
            // ---------------- LSE (exp-trick) ----------------
            float Ec[LL];
            #pragma unroll
            for (int i = 0; i < LL; ++i) Ec[i] = __expf(trans[i * LL + jj]);

            LDG(A, 0);
            int mkc = mrow[lane], mkn = 0;
            float a = act ? (startT[lane] + A0) : -INFF;
            float M = 0.f;

#define LCORE(EMIT, BIT) do { \
    float x_ = __expf(a - M); \
    float s0_ = rlf(x_, 0) * Ec[0]; \
    _Pragma("unroll") for (int i_ = 1; i_ < 7; ++i_)  s0_ = fmaf(rlf(x_, i_), Ec[i_], s0_); \
    float s1_ = rlf(x_, 7) * Ec[7]; \
    _Pragma("unroll") for (int i_ = 8; i_ < 14; ++i_) s1_ = fmaf(rlf(x_, i_), Ec[i_], s1_); \
    float s2_ = rlf(x_, 14) * Ec[14]; \
    _Pragma("unroll") for (int i_ = 15; i_ < 21; ++i_) s2_ = fmaf(rlf(x_, i_), Ec[i_], s2_); \
    float Ss_ = (s0_ + s1_) + s2_; \
    bool mt_ = ((mm >> (BIT)) & 1ull) != 0ull; \
    float an_ = M + __logf(Ss_) + (EMIT); \
    a = (mt_ && act) ? an_ : a; \
} while (0)

#define LGROUP(P, G, BITB) do { int tb4_ = (G) * 4; \
    if (tb4_ != 0) LCORE(P##0, (BITB) + 0); \
    LCORE(P##1, (BITB) + 1); \
    LCORE(P##2, (BITB) + 2); \
    LCORE(P##3, (BITB) + 3); \
} while (0)

            for (int q = 0; q < 8; ++q) {
                unsigned long long mm = __ballot(mkc != 0);
                if (q < 7) mkn = mrow[(q + 1) * 64 + lane];
                for (int gp = 0; gp < 8; ++gp) {
                    if ((gp & 1) == 0) M = rlmax21(a);   // every 16 steps (same cadence as R6)
                    int g = q * 16 + gp * 2;
                    LDG(B, g + 1);
                    LGROUP(A, g, gp * 8);
                    if (g + 2 < 128) LDG(A, g + 2);
                    LGROUP(B, g + 1, gp * 8 + 4);
                }
                mkc = mkn;
            }
#undef LCORE
#undef LGROUP
            float f = act ? (a + endT[lane]) : -INFF;
            float m = wmax64(f);
            float p = act ? __expf(f - m) : 0.f;
            #pragma unroll
            for (int off = 32; off; off >>= 1) p += __shfl_xor(p, off);
            if (lane == 0) denom[b] = m + __logf(p);
        }
#undef LDG
    } else {
        // ---------------- numerator ----------------
        int b = bid - 128;
        const int* lrow = labels + b * SS;
        const int* arow = attn + b * SS;
        float psum = 0.f;
        int pcnt = 0;
        for (int s = 0; s < 8; ++s) {
            int t = s * 64 + lane;
            int lab = lrow[t];
            int mk = arow[t];
            int valid = (t == 0) ? 1 : ((mk != 0 && lab >= 0) ? 1 : 0);
            if (t >= 1 && valid) {
                int tag = (lab < 0) ? 0 : lab;
                int labp = lrow[t - 1];
                int tagp = (t == 1) ? 0 : ((labp < 0) ? 0 : labp);
                psum += trans[tagp * LL + tag] + em[((size_t)b * SS + t) * LL + tag];
            }
            pcnt += valid;
        }
        #pragma unroll
        for (int off = 32; off; off >>= 1) {
            psum += __shfl_xor(psum, off);
            pcnt += __shfl_xor(pcnt, off);
        }
        int ts = pcnt - 1;
        int labL = lrow[ts];
        int tagL = (ts == 0) ? 0 : ((labL < 0) ? 0 : labL);
        if (lane == 0)
            num[b] = startT[0] + em[(size_t)b * SS * LL + 0] + psum + endT[tagL];
    }
}

// ---------------- K3: backtrack (S transposed [b][j][t]) ----------------
__global__ __launch_bounds__(256) void k_back(const float* __restrict__ S,
                                              const int* __restrict__ attn,
                                              const float* __restrict__ endT,
                                              const float* __restrict__ trans,
                                              int* __restrict__ tagsOut) {
    __shared__ unsigned char pred[SS * 24];
    __shared__ unsigned char mapL[64 * 32];
    __shared__ float Tl[441];
    int tid = threadIdx.x, b = blockIdx.x;
    const float* SB = S + (size_t)b * (LL * SS);
    for (int i = tid; i < 441; i += 256) Tl[i] = trans[i];
    __syncthreads();

    for (int u = tid; u < 511 * LL; u += 256) {
        int t = 1 + u / LL;
        int j = u - (u / LL) * LL;
        unsigned int pj = (unsigned int)j;
        if (attn[b * SS + t] != 0) {
            float bv = SB[0 * SS + (t - 1)] + Tl[j];
            unsigned int bi = 0;
            #pragma unroll
            for (int i = 1; i < LL; ++i) {
                float c = SB[i * SS + (t - 1)] + Tl[i * LL + j];
                bool g = c > bv;            // strict > : first max wins
                bv = g ? c : bv;
                bi = g ? (unsigned int)i : bi;
            }
            pj = bi;
        }
        pred[t * 24 + j] = (unsigned char)pj;
    }
    __syncthreads();

    if (tid < 64) {
        int lane = tid;
        float f = (lane < LL) ? (SB[lane * SS + (SS - 1)] + endT[lane]) : -INFF;
        float m = wmax64(f);
        unsigned long long msk = __ballot(f == m);
        int best_last = __ffsll(msk) - 1;

        int tlo = 8 * lane + 1;
        int thi = 8 * lane + 8; if (thi > 511) thi = 511;
        unsigned int BM[LL];
        #pragma unroll
        for (int s = 0; s < LL; ++s) BM[s] = s;
        for (int k = 0; k < 8; ++k) {
            int t = thi - k;
            if (t >= tlo) {
                #pragma unroll
                for (int s = 0; s < LL; ++s) BM[s] = pred[t * 24 + BM[s]];
            }
        }
        #pragma unroll
        for (int s = 0; s < LL; ++s) mapL[lane * 32 + s] = (unsigned char)BM[s];

        #pragma unroll
        for (int kk = 1; kk < 64; kk <<= 1) {
            int p = lane + kk;
            bool vld = p < 64;
            int pp = vld ? p : 0;
            unsigned int P[LL];
            #pragma unroll
            for (int s = 0; s < LL; ++s) {
                unsigned int v = mapL[pp * 32 + s];
                P[s] = vld ? v : (unsigned int)s;
            }
            unsigned int N[LL];
            #pragma unroll
            for (int s = 0; s < LL; ++s) N[s] = mapL[lane * 32 + P[s]];
            #pragma unroll
            for (int s = 0; s < LL; ++s) mapL[lane * 32 + s] = (unsigned char)N[s];
        }

        int st8 = mapL[lane * 32 + best_last];
        int nxt = __shfl(st8, lane + 1);
        int cur = (lane == 63) ? best_last : nxt;
        for (int k = 0; k < 8; ++k) {
            int t = thi - k;
            if (t >= tlo) {
                tagsOut[b * SS + t] = cur;
                cur = pred[t * 24 + cur];
            }
        }
        if (lane == 0) tagsOut[b * SS] = cur;
    }
}

// ---------------- K4: loss + one-hot logits ----------------
__global__ __launch_bounds__(256) void k_out(const float* __restrict__ num,
                                             const float* __restrict__ denom,
                                             const int* __restrict__ tagsW,
                                             const int* __restrict__ attn,
                                             float* __restrict__ out) {
    int gid = blockIdx.x * 256 + threadIdx.x;
    if ((int)blockIdx.x == (int)gridDim.x - 1 && threadIdx.x < 64) {
        float llh = num[threadIdx.x] - denom[threadIdx.x];
        #pragma unroll
        for (int off = 32; off; off >>= 1) llh += __shfl_xor(llh, off);
        if (threadIdx.x == 0) out[0] = -llh / (float)BB;
    }
    if (gid < BB * SS * LL) {
        int bt = gid / LL, l = gid % LL;
        int tag = tagsW[bt];
        int mk  = attn[bt];
        out[1 + gid] = (mk && tag == l) ? 1.f : 0.f;
    }
}

extern "C" void kernel_launch(void* const* d_in, const int* in_sizes, int n_in,
                              void* d_out, int out_size, void* d_ws, size_t ws_size,
                              hipStream_t stream) {
    const float* hidden = (const float*)d_in[0];
    const int*   attn   = (const int*)d_in[1];
    const int*   labels = (const int*)d_in[2];
    const float* W      = (const float*)d_in[3];
    const float* bias   = (const float*)d_in[4];
    const float* startT = (const float*)d_in[5];
    const float* endT   = (const float*)d_in[6];
    const float* trans  = (const float*)d_in[7];
    float* out = (float*)d_out;

    float* wsf   = (float*)d_ws;
    float* em    = wsf;                       // BB*SS*LL
    float* num   = wsf + (size_t)BB * SS * LL;
    float* denom = num + 64;
    int*   tags  = (int*)(denom + 64);        // BB*SS ints
    float* Sbuf  = out + 1;                   // Viterbi scores [b][j][t]; overwritten by k_out

    hipLaunchKernelGGL(k_emis, dim3(256), dim3(256), 0, stream, hidden, W, bias, em);
    hipLaunchKernelGGL(k_scan, dim3(192), dim3(64),  0, stream, em, attn, labels,
                       startT, endT, trans, num, denom, Sbuf);
    hipLaunchKernelGGL(k_back, dim3(64),  dim3(256), 0, stream, Sbuf, attn, endT, trans, tags);
    int oh_blocks = (BB * SS * LL + 255) / 256;   // 2688 exactly
    hipLaunchKernelGGL(k_out,  dim3(oh_blocks + 1), dim3(256), 0, stream,
                       num, denom, tags, attn, out);
}